// Round 5
// baseline (165.389 us; speedup 1.0000x reference)
//
#include <hip/hip_runtime.h>
#include <hip/hip_bf16.h>

#define B_ 128
#define F_ 100
#define N_ 512
#define H_ 1024
#define P_ 512
#define E_ 8
#define BK 64
#define AROWS 112  // staged A rows (M=100 rounded to DMA granularity of 8)

typedef __attribute__((ext_vector_type(8))) short bf16x8;
typedef __attribute__((ext_vector_type(4))) float f32x4;

// async global->LDS DMA, 16B/lane, LDS dest = wave-uniform base + lane*16
#define GLOAD16(g, l) __builtin_amdgcn_global_load_lds(                      \
    (const __attribute__((address_space(1))) void*)(g),                      \
    (__attribute__((address_space(3))) void*)(l), 16, 0, 0)

static __device__ __forceinline__ short f2bf(float f) {
    __hip_bfloat16 h = __float2bfloat16(f);
    short s;
    __builtin_memcpy(&s, &h, sizeof(s));
    return s;
}

// ONE prep kernel, grid sections:
//   [0,3200)      convert x [B][F][N] fp32 -> xbf [12800][N] bf16 (linear)
//   [3200,4224)   transpose W1 [E][512][1024] -> W1T [E][1024][512] bf16
//   [4224,5248)   transpose W2 [E][1024][512] -> W2T [E][512][1024] bf16
//   5248          tile table sorted by expert (data stays in trial order):
//                 ttab[slot]=(trial,eid); adjacent slots share an expert
//                 almost always -> pair (2p,2p+1) shares a B panel.
__global__ __launch_bounds__(256) void prep(
    const float* __restrict__ x, const float* __restrict__ W1,
    const float* __restrict__ W2, const int* __restrict__ eid,
    short* __restrict__ xbf, short* __restrict__ W1T, short* __restrict__ W2T,
    int2* __restrict__ ttab) {
    __shared__ float tile[64][65];
    __shared__ int scnt[E_], sbase[E_];
    const int bx = blockIdx.x;
    const int t = threadIdx.x;
    if (bx < 3200) {  // ---- convert x ----
        const int g = bx * 256 + t;
        const int col = (g & 63) * 8;
        const int row = g >> 6;  // 0..12799
        const float* xp = x + (size_t)row * N_ + col;
        const float4 v0 = *(const float4*)(xp);
        const float4 v1 = *(const float4*)(xp + 4);
        union { short s[8]; uint4 u; } o;
        o.s[0] = f2bf(v0.x); o.s[1] = f2bf(v0.y);
        o.s[2] = f2bf(v0.z); o.s[3] = f2bf(v0.w);
        o.s[4] = f2bf(v1.x); o.s[5] = f2bf(v1.y);
        o.s[6] = f2bf(v1.z); o.s[7] = f2bf(v1.w);
        *(uint4*)(xbf + (size_t)row * N_ + col) = o.u;
    } else if (bx < 5248) {  // ---- weight transpose+convert ----
        const float* W; short* WT; int R, C, r0, c0, e;
        if (bx < 4224) {
            const int idx = bx - 3200;
            e = idx >> 7; const int i = idx & 127;
            W = W1; WT = W1T; R = N_; C = H_;
            r0 = (i >> 4) * 64; c0 = (i & 15) * 64;
        } else {
            const int idx = bx - 4224;
            e = idx >> 7; const int i = idx & 127;
            W = W2; WT = W2T; R = H_; C = P_;
            r0 = (i & 15) * 64; c0 = (i >> 4) * 64;
        }
        const float* Wp = W + (size_t)e * R * C;
        short* WTp = WT + (size_t)e * C * R;
        {
            const int c4 = (t & 15) * 4, r = t >> 4;
#pragma unroll
            for (int p = 0; p < 4; p++) {
                const int row = p * 16 + r;
                const float4 v = *(const float4*)(Wp + (size_t)(r0 + row) * C + c0 + c4);
                tile[row][c4 + 0] = v.x; tile[row][c4 + 1] = v.y;
                tile[row][c4 + 2] = v.z; tile[row][c4 + 3] = v.w;
            }
        }
        __syncthreads();
        {
            const int r8 = (t & 7) * 8, cl = t >> 3;
#pragma unroll
            for (int p = 0; p < 2; p++) {
                const int c = p * 32 + cl;
                union { short s[8]; uint4 u; } o;
#pragma unroll
                for (int j = 0; j < 8; j++) o.s[j] = f2bf(tile[r8 + j][c]);
                *(uint4*)(&WTp[(size_t)(c0 + c) * R + r0 + r8]) = o.u;
            }
        }
    } else {  // ---- tile-table sort (one block) ----
        if (t < E_) scnt[t] = 0;
        __syncthreads();
        int my_e = 0;
        if (t < B_) { my_e = eid[t]; atomicAdd(&scnt[my_e], 1); }
        __syncthreads();
        if (t == 0) {
            int s = 0;
            for (int i = 0; i < E_; i++) { sbase[i] = s; s += scnt[i]; }
        }
        __syncthreads();
        if (t < B_) {
            const int pos = atomicAdd(&sbase[my_e], 1);
            ttab[pos] = make_int2(t, my_e);
        }
    }
}

// PAIRED GEMM: one block = TWO trials (expert-sorted adjacent slots 2p,2p+1)
// x one 128-col n-tile. 512 threads = 8 waves = two 4-wave groups; group g
// runs the proven per-wave 2x2 code (wave-tile 64x64... rows 112 staged) on
// trial g's A panel. B panel (W1T/W2T rows n0..n0+127) is staged ONCE and
// shared by both groups when the pair shares an expert (the common case);
// rare dual-expert pairs stage a second B panel into B1. LDS:
//   A0[112*64] A1[112*64] B0[128*64] B1[128*64] bf16 = 61440 B -> 2 blk/CU.
// vs R3: staged global traffic -25%, per-CU barriers halved, gemm1
// occupancy 8->16 waves/CU. K-loop = simple full-drain 2-phase (measured
// equal to counted-vmcnt in R3). Epilogue: two sequential group passes over
// the shared 32 KiB LDS scratch (per-wave 8 KiB), 16B coalesced stores.
// FIRST:  act[(trial*100+row)][col] = softsign(A @ W1T^T + b1), bf16
// !FIRST: out[trial][row][col]      = A @ W2T^T + b2, fp32   (row < 100)
template <int KDIM, bool FIRST>
__global__ __launch_bounds__(512, 4) void gemm_pair(
    const short* __restrict__ A,     // [B_*F_+128pad][KDIM] bf16, K-contig
    const short* __restrict__ WT,    // [E][NCOLS][KDIM] bf16, K-contig
    const float* __restrict__ bias,  // [E][NCOLS]
    const int2* __restrict__ ttab,   // [B_] (trial, expert), expert-sorted
    short* __restrict__ actout,      // FIRST
    float* __restrict__ out)         // !FIRST
{
    constexpr int NCOLS = FIRST ? H_ : P_;
    constexpr int BN = 128, NI = 4;
    __shared__ short sbuf[2 * AROWS * BK + 2 * BN * BK];  // 61440 B
    // pair p -> slots (2p, 2p+1); XCD = blockIdx.x&7 owns 8 pairs = 16
    // expert-contiguous slots (blockIdx.y*64 is a multiple of 8 -> same XCD).
    const int pair = (blockIdx.x & 7) * 8 + (blockIdx.x >> 3);
    const int2 te0 = ttab[2 * pair], te1 = ttab[2 * pair + 1];
    const int n0 = blockIdx.y * BN;
    const int t = threadIdx.x;
    const int lane = t & 63, w = t >> 6;       // 8 waves
    const int g = w >> 2, wsub = w & 3;        // trial-group, wave-in-group
    const int trial = g ? te1.x : te0.x;
    const int e     = g ? te1.y : te0.y;
    const bool dual = (te0.y != te1.y);        // block-uniform
    const int wm = (wsub >> 1) * 64, wn = (wsub & 1) * 64;
    const int l15 = lane & 15, quad = lane >> 4;
    const int lr = lane >> 3;                  // staging row 0..7
    const int lc = (((lane & 7) ^ lr) * 8);    // XOR-swizzled col chunk

    short* sA = sbuf + g * (AROWS * BK);
    short* sB = sbuf + 2 * (AROWS * BK) + ((dual && g) ? BN * BK : 0);

    f32x4 acc[4][NI];
#pragma unroll
    for (int mi = 0; mi < 4; mi++)
#pragma unroll
        for (int ni = 0; ni < NI; ni++)
            acc[mi][ni] = (f32x4)(0.0f);

    // hoist bias (depends on ni only; per-group expert)
    float bv[NI];
#pragma unroll
    for (int ni = 0; ni < NI; ni++)
        bv[ni] = bias[(size_t)e * NCOLS + n0 + wn + ni * 16 + l15];

    const short* Ap = A + (size_t)trial * F_ * KDIM;
    const short* Bp = WT + ((size_t)e * NCOLS + n0) * KDIM;

    for (int k0 = 0; k0 < KDIM; k0 += BK) {
        // ---- stage: group g loads its A; B loaded once (twice if dual) ----
#pragma unroll
        for (int i = 0; i < 4; i++) {
            const int rb = wsub * 32 + i * 8;
            if (rb < AROWS)  // wave-uniform; rows 112..127 never read
                GLOAD16(Ap + (size_t)(rb + lr) * KDIM + k0 + lc, &sA[rb * BK]);
        }
        if (g == 0 || dual) {  // wave-uniform (g per wave, dual per block)
#pragma unroll
            for (int i = 0; i < 4; i++) {
                const int rb = wsub * 32 + i * 8;  // 4 waves cover 128 rows
                GLOAD16(Bp + (size_t)(rb + lr) * KDIM + k0 + lc, &sB[rb * BK]);
            }
        }
        __syncthreads();
        // ---- compute: identical proven per-wave 2x2 inner loop ----
#pragma unroll
        for (int ks = 0; ks < 2; ks++) {
            const int sw = (((ks * 4 + quad) ^ (l15 & 7)) * 8);
            bf16x8 af, bfr[NI];
#pragma unroll
            for (int ni = 0; ni < NI; ni++)
                bfr[ni] = *(const bf16x8*)(&sB[(wn + ni * 16 + l15) * BK + sw]);
#pragma unroll
            for (int mi = 0; mi < 4; mi++) {
                if (wm + mi * 16 < F_) {  // wave-uniform; indices constant
                    af = *(const bf16x8*)(&sA[(wm + mi * 16 + l15) * BK + sw]);
#pragma unroll
                    for (int ni = 0; ni < NI; ni++)
                        acc[mi][ni] = __builtin_amdgcn_mfma_f32_16x16x32_bf16(af, bfr[ni], acc[mi][ni], 0, 0, 0);
                }
            }
        }
        __syncthreads();  // protects restage; final one protects epilogue
    }

    // ---- epilogue: two sequential group passes over shared LDS scratch ----
    // C/D frag layout: col=lane&15, row=quad*4+reg.
    auto epi = [&]() {
        if constexpr (FIRST) {
            short* sW = sbuf + wsub * 4096;  // 64 rows x 64 bf16/wave (8 KiB)
#pragma unroll
            for (int mi = 0; mi < 4; mi++) {
#pragma unroll
                for (int ni = 0; ni < 4; ni++) {
                    const int cl = ni * 16 + l15;
#pragma unroll
                    for (int r = 0; r < 4; r++) {
                        const int rl = mi * 16 + quad * 4 + r;  // 0..63
                        float v = acc[mi][ni][r] + bv[ni];
                        v = v / (1.0f + fabsf(v));  // softsign, SCALE=1
                        sW[rl * 64 + (((cl >> 3) ^ (rl & 7)) * 8) + (cl & 7)] = f2bf(v);
                    }
                }
            }
#pragma unroll
            for (int i = 0; i < 8; i++) {
                const int rl = i * 8 + lr;        // 0..63 (rl&7 == lr)
                const int c = lane & 7;
                const bf16x8 v = *(const bf16x8*)(&sW[rl * 64 + ((c ^ lr) * 8)]);
                const int grow = wm + rl;
                if (grow < F_)
                    *(bf16x8*)(&actout[((size_t)trial * F_ + grow) * H_ + n0 + wn + c * 8]) = v;
            }
        } else {
            float* fW = (float*)(sbuf) + wsub * 2048;  // 64r x 32c fp32/wave
#pragma unroll
            for (int pass = 0; pass < NI; pass += 2) {
#pragma unroll
                for (int mi = 0; mi < 4; mi++) {
#pragma unroll
                    for (int nj = 0; nj < 2; nj++) {
                        const int cl = nj * 16 + l15;   // 0..31
#pragma unroll
                        for (int r = 0; r < 4; r++) {
                            const int rl = mi * 16 + quad * 4 + r;  // 0..63
                            fW[rl * 32 + (((cl >> 2) ^ (rl & 7)) * 4) + (cl & 3)] =
                                acc[mi][pass + nj][r] + bv[pass + nj];
                        }
                    }
                }
#pragma unroll
                for (int i = 0; i < 8; i++) {
                    const int rl = i * 8 + lr;           // 0..63 (rl&7 == lr)
                    const int c = lane & 7;              // 8 chunks x 16B
                    const float4 v = *(const float4*)(&fW[rl * 32 + ((c ^ lr) * 4)]);
                    const int grow = wm + rl;
                    if (grow < F_)
                        *(float4*)(&out[((size_t)trial * F_ + grow) * P_ + n0 + wn + pass * 16 + c * 4]) = v;
                }
                // per-wave private buffer; same-wave RAW across passes is
                // ordered by compiler-inserted lgkmcnt -> no barrier needed.
            }
        }
    };
    if (g == 0) epi();
    __syncthreads();
    if (g == 1) epi();
}

extern "C" void kernel_launch(void* const* d_in, const int* in_sizes, int n_in,
                              void* d_out, int out_size, void* d_ws, size_t ws_size,
                              hipStream_t stream) {
    const float* x  = (const float*)d_in[0];
    const int* eid  = (const int*)d_in[1];
    const float* W1 = (const float*)d_in[2];
    const float* b1 = (const float*)d_in[3];
    const float* W2 = (const float*)d_in[4];
    const float* b2 = (const float*)d_in[5];
    float* out = (float*)d_out;

    char* ws = (char*)d_ws;
    short* W1T = (short*)(ws);                          // [E][H][N]      8 MiB
    short* W2T = (short*)(ws + (size_t)(8u << 20));     // [E][P][H]      8 MiB
    short* act = (short*)(ws + (size_t)(16u << 20));    // [12800+128][H] ~26.5 MiB
    short* xbf = (short*)(ws + (size_t)(43u << 20));    // [12800+128][N] ~13.3 MiB
    int2* ttab = (int2*)(ws + (size_t)(57u << 20));     // [B_]

    prep<<<dim3(5249), 256, 0, stream>>>(x, W1, W2, eid, xbf, W1T, W2T, ttab);
    // gemm1: 64 pair-blocks x 8 n-tiles = 512 blocks, 2/CU, 16 waves/CU.
    gemm_pair<N_, true><<<dim3(64, H_ / 128), 512, 0, stream>>>(xbf, W1T, b1, ttab, act, nullptr);
    // gemm2: 64 pair-blocks x 4 n-tiles = 256 blocks, 1/CU, 8 waves/CU.
    gemm_pair<H_, false><<<dim3(64, P_ / 128), 512, 0, stream>>>(act, W2T, b2, ttab, nullptr, out);
}